// Round 2
// baseline (275.713 us; speedup 1.0000x reference)
//
#include <hip/hip_runtime.h>

// SystemIDModel: y[k] = poly8(x2[k]) - x1[k] - R0*u[k]
//   x1[k] = A00*x1[k-1] + B0*u[k-1]   (x1[0]=0)   A00 = exp(-dt/(Rp*Cp)), B0 = Rp*(1-A00)
//   x2[k] = x2[k-1] + B1*u[k-1]       (x2[0]=1)   B1 = -1/5400
//
// SINGLE-DISPATCH fused scan, NO grid.sync (round-1 showed cg::grid.sync costs
// ~100 us at 1024 blocks: k_fused 122 us @ 1.9% VALUBusy).
// Structure: decoupled publish/poll.
//   Phase 1: load u into registers (only read of u), thread serial scan,
//            wave shuffle scan, block reduce -> publish (aggW[b], aggP[b])
//            with release stores + index-salted double-magic flags.
//   Phase 2: each thread polls ONLY the flags it needs (aggP[j], j in its
//            fixed slice of [0,b)), then the SAME deterministic fixed-order
//            redundant reduce as the verified 2-dispatch kernel. carryW needs
//            only aggW[b-1] (A00^CHUNK underflows to exactly 0 here; general
//            fallback retained). Then assemble prefixes from still-live
//            registers/LDS and emit.
// Determinism: summation order identical to the verified kB (per-thread index
// order -> fixed shuffle tree -> fixed wave order); carries are single values.
// Timing independence: values read are unique published values; polling only
// affects WHEN, never WHAT.
// Deadlock safety: 1024 blocks at 4 blocks/CU (32 VGPR, 48B LDS) x 256 CU ->
// entire grid co-resident; publishes happen before any wait.
// Poison safety: flags require flagA[j]==MAGIC1^j AND flagB[j]==MAGIC2+j —
// no uniform fill pattern can satisfy both for any j.

constexpr int BLOCK = 256;
constexpr int TPER  = 16;
constexpr int CHUNK = BLOCK * TPER;    // 4096
constexpr int NTOT  = 4194304;
constexpr int NB    = NTOT / CHUNK;    // 1024
constexpr int WPB   = BLOCK / 64;      // 4 waves per block
constexpr int APT   = NB / BLOCK;      // aggP entries per thread = 4

constexpr unsigned MAGIC1 = 0x1B7F3A55u;
constexpr unsigned MAGIC2 = 0x9C24E16Bu;

__global__ __launch_bounds__(BLOCK, 4) void k_scan(
    const float* __restrict__ u,
    const float* __restrict__ Rp_p, const float* __restrict__ Cp_p,
    const float* __restrict__ R0_p, const float* __restrict__ ac,
    float* __restrict__ aggW, float* __restrict__ aggP,
    unsigned* __restrict__ flagA, unsigned* __restrict__ flagB,
    float* __restrict__ out)
{
    __shared__ float LW[WPB], LP[WPB];
    __shared__ float sRed[WPB];
    __shared__ float sCW;

    const int b = blockIdx.x, t = threadIdx.x;
    const int lane = t & 63, w = t >> 6;

    const float Rp  = Rp_p[0];
    const float invRC = 1.0f / (Rp * Cp_p[0]);
    const float A00 = __expf(-invRC);
    const float B0  = Rp * (1.0f - A00);
    const float B1  = -1.0f / 5400.0f;                   // -eta*dt/(1.5*3600)
    const float a2 = A00 * A00, a4 = a2 * a2, a8 = a4 * a4;
    const float f16 = a8 * a8;                           // A00^TPER
    float f1024 = f16;
    for (int i = 0; i < 6; ++i) f1024 *= f1024;          // A00^1024 (0.0f here)
    const float dC = (f1024 * f1024) * (f1024 * f1024);  // A00^CHUNK (0.0f here)

    // ---- Phase 1: load chunk (the ONLY read of u), thread scan, wave scan ----
    const size_t base = (size_t)b * CHUNK + (size_t)t * TPER;
    const float4* up = (const float4*)(u + base);
    float4 v[4];
    v[0] = up[0]; v[1] = up[1]; v[2] = up[2]; v[3] = up[3];
    const float* uu = (const float*)v;

    float s = 0.0f, p = 0.0f;
#pragma unroll
    for (int i = 0; i < TPER; ++i) { s = fmaf(A00, s, uu[i]); p += uu[i]; }

    float fk = f16;
#pragma unroll
    for (int k = 1; k < 64; k <<= 1) {
        const float sw = __shfl_up(s, k, 64);
        const float pw = __shfl_up(p, k, 64);
        if (lane >= k) { s = fmaf(sw, fk, s); p += pw; }
        fk *= fk;
    }
    if (lane == 63) { LW[w] = s; LP[w] = p; }
    __syncthreads();

    // ---- publish own aggregate ASAP (minimizes consumers' wait) ----
    if (t == 0) {
        float W = LW[0], P = LP[0];
        for (int q = 1; q < WPB; ++q) { W = fmaf(W, f1024, LW[q]); P += LP[q]; }
        __hip_atomic_store(&aggW[b], W, __ATOMIC_RELAXED, __HIP_MEMORY_SCOPE_AGENT);
        __hip_atomic_store(&aggP[b], P, __ATOMIC_RELAXED, __HIP_MEMORY_SCOPE_AGENT);
        // release: data stores above are visible before either flag
        __hip_atomic_store(&flagA[b], MAGIC1 ^ (unsigned)b,
                           __ATOMIC_RELEASE, __HIP_MEMORY_SCOPE_AGENT);
        __hip_atomic_store(&flagB[b], MAGIC2 + (unsigned)b,
                           __ATOMIC_RELEASE, __HIP_MEMORY_SCOPE_AGENT);
    }

    // ---- Phase 2a: carryP — poll + fixed-order redundant reduce of aggP[0..b) ----
    float pc = 0.0f;
#pragma unroll
    for (int i = 0; i < APT; ++i) {
        const int j = t * APT + i;
        if (j < b) {
            while (__hip_atomic_load(&flagA[j], __ATOMIC_ACQUIRE,
                                     __HIP_MEMORY_SCOPE_AGENT) != (MAGIC1 ^ (unsigned)j))
                __builtin_amdgcn_s_sleep(1);
            while (__hip_atomic_load(&flagB[j], __ATOMIC_ACQUIRE,
                                     __HIP_MEMORY_SCOPE_AGENT) != (MAGIC2 + (unsigned)j))
                __builtin_amdgcn_s_sleep(1);
            pc += __hip_atomic_load(&aggP[j], __ATOMIC_RELAXED, __HIP_MEMORY_SCOPE_AGENT);
        }
    }
#pragma unroll
    for (int off = 32; off; off >>= 1) pc += __shfl_down(pc, off, 64);
    if (lane == 0) sRed[w] = pc;

    // ---- carryW: only aggW[b-1] needed (dC==0); general fallback kept ----
    if (t == 0) {
        float cW = 0.0f;
        if (b > 0) {
            if (dC == 0.0f) {
                const int j = b - 1;
                while (__hip_atomic_load(&flagA[j], __ATOMIC_ACQUIRE,
                                         __HIP_MEMORY_SCOPE_AGENT) != (MAGIC1 ^ (unsigned)j))
                    __builtin_amdgcn_s_sleep(1);
                while (__hip_atomic_load(&flagB[j], __ATOMIC_ACQUIRE,
                                         __HIP_MEMORY_SCOPE_AGENT) != (MAGIC2 + (unsigned)j))
                    __builtin_amdgcn_s_sleep(1);
                cW = __hip_atomic_load(&aggW[j], __ATOMIC_RELAXED,
                                       __HIP_MEMORY_SCOPE_AGENT);
            } else {                                     // general fallback
                for (int j = 0; j < b; ++j) {
                    while (__hip_atomic_load(&flagA[j], __ATOMIC_ACQUIRE,
                                             __HIP_MEMORY_SCOPE_AGENT) != (MAGIC1 ^ (unsigned)j))
                        __builtin_amdgcn_s_sleep(1);
                    while (__hip_atomic_load(&flagB[j], __ATOMIC_ACQUIRE,
                                             __HIP_MEMORY_SCOPE_AGENT) != (MAGIC2 + (unsigned)j))
                        __builtin_amdgcn_s_sleep(1);
                    cW = fmaf(cW, dC, __hip_atomic_load(&aggW[j], __ATOMIC_RELAXED,
                                                        __HIP_MEMORY_SCOPE_AGENT));
                }
            }
        }
        sCW = cW;
    }
    __syncthreads();                                     // sRed/sCW ready

    // ---- Phase 2b: assemble per-thread exclusive prefixes (s, p, LW, LP live) ----
    float carryP_blk = 0.0f;
#pragma unroll
    for (int q = 0; q < WPB; ++q) carryP_blk += sRed[q];

    float cw = 0.0f, cp = 0.0f;                          // previous-wave carries
    for (int q = 0; q < w; ++q) { cw = fmaf(cw, f1024, LW[q]); cp += LP[q]; }

    float fw = 1.0f;                                     // f1024^w
    for (int q = 0; q < w; ++q) fw *= f1024;

    float fl = 1.0f, bse = f16;                          // f16^lane (square-multiply)
#pragma unroll
    for (int k = 0; k < 6; ++k) { if (lane & (1 << k)) fl *= bse; bse *= bse; }

    const float upW = __shfl_up(s, 1, 64);
    const float upP = __shfl_up(p, 1, 64);
    float Wcur = (lane ? upW : 0.0f) + fmaf(sCW, fw, cw) * fl;  // W at elem base
    float Pcur = (lane ? upP : 0.0f) + cp + carryP_blk;         // P at elem base

    // ---- emit 16 outputs/thread ----
    const float R0f = R0_p[0];
    float af[9];
#pragma unroll
    for (int i = 0; i < 9; ++i) af[i] = ac[i];

    float4 o[4];
    float* oy = (float*)o;
#pragma unroll
    for (int i = 0; i < TPER; ++i) {
        const float x2 = fmaf(B1, Pcur, 1.0f);           // INITIAL_X2 = 1
        float poly = af[8];
#pragma unroll
        for (int j = 7; j >= 0; --j) poly = fmaf(poly, x2, af[j]);
        oy[i] = poly - B0 * Wcur - R0f * uu[i];
        Wcur = fmaf(A00, Wcur, uu[i]);                   // emit state BEFORE update
        Pcur += uu[i];
    }
    float4* op = (float4*)(out + base);
    op[0] = o[0]; op[1] = o[1]; op[2] = o[2]; op[3] = o[3];
}

extern "C" void kernel_launch(void* const* d_in, const int* in_sizes, int n_in,
                              void* d_out, int out_size, void* d_ws, size_t ws_size,
                              hipStream_t stream) {
    const float* u    = (const float*)d_in[0];
    const float* Rp_p = (const float*)d_in[1];
    const float* Cp_p = (const float*)d_in[2];
    const float* R0_p = (const float*)d_in[3];
    const float* ac   = (const float*)d_in[4];
    float* out = (float*)d_out;

    float*    wsW   = (float*)d_ws;                  // [NB]
    float*    wsP   = (float*)d_ws + NB;             // [NB]
    unsigned* wsFA  = (unsigned*)((float*)d_ws + 2 * NB);   // [NB]
    unsigned* wsFB  = (unsigned*)((float*)d_ws + 3 * NB);   // [NB]

    k_scan<<<NB, BLOCK, 0, stream>>>(u, Rp_p, Cp_p, R0_p, ac,
                                     wsW, wsP, wsFA, wsFB, out);
}

// Round 3
// 83.879 us; speedup vs baseline: 3.2870x; 3.2870x over previous
//
#include <hip/hip_runtime.h>

// SystemIDModel: y[k] = poly8(x2[k]) - x1[k] - R0*u[k]
//   x1[k] = A00*x1[k-1] + B0*u[k-1]   (x1[0]=0)   A00 = exp(-dt/(Rp*Cp)), B0 = Rp*(1-A00)
//   x2[k] = x2[k-1] + B1*u[k-1]       (x2[0]=1)   B1 = -1/5400
//
// LESSON (rounds 1-2): intra-kernel cross-block sync on MI355X costs ~100-200us
// (grid.sync: 122us @ 1.9% VALUBusy; flag-poll lookback: 218us @ 1.1%) because
// agent-scope release/acquire must cross 8 non-coherent XCD L2s. The kernel
// boundary IS the efficient device-wide barrier (~2us). So: 2 plain dispatches.
//
// vs the 84.6us baseline 2-dispatch version:
//   kA: pure chunk-sum reduce (P only) — weighted W shuffle-scan DROPPED on the
//       fast path. x1's decay kernel A00^d hits exactly 0.0f at d=128 for
//       A00 = e^-1 (e^-128 ~ 2.6e-56), so kB recomputes the W carry from a
//       128-element halo instead of needing aggW from kA.
//   kB: wave 0 computes W_base = sum_{d=1..128} A00^(d-1) * u[base-d] via one
//       weighted shuffle reduce (512B extra read/block). Everything else
//       (aggP redundant reduce, wave scans, emit) identical to the verified
//       baseline. General-A00 fallback (A00^128 != 0) keeps the aggW path.

constexpr int BLOCK = 256;
constexpr int TPER  = 16;
constexpr int CHUNK = BLOCK * TPER;    // 4096
constexpr int NTOT  = 4194304;
constexpr int NB    = NTOT / CHUNK;    // 1024
constexpr int WPB   = BLOCK / 64;      // 4 waves per block
constexpr int APT   = NB / BLOCK;      // aggP entries per thread in kB = 4

// ---------------- Kernel A: per-chunk aggregates ----------------
__global__ __launch_bounds__(BLOCK, 4) void kA_agg(
    const float* __restrict__ u,
    const float* __restrict__ Rp_p, const float* __restrict__ Cp_p,
    float* __restrict__ aggW, float* __restrict__ aggP)
{
    __shared__ float LW[WPB], LP[WPB];
    const int b = blockIdx.x, t = threadIdx.x;
    const int lane = t & 63, w = t >> 6;

    const float invRC = 1.0f / (Rp_p[0] * Cp_p[0]);
    const float A00 = __expf(-invRC);
    const float a2 = A00 * A00, a4 = a2 * a2, a8 = a4 * a4;
    const float f16 = a8 * a8;                           // A00^16
    const float f32p = f16 * f16, f64p = f32p * f32p;
    const float f128 = f64p * f64p;                      // A00^128
    const bool FAST = (f128 == 0.0f);                    // halo path valid

    const float4* up = (const float4*)(u + (size_t)b * CHUNK + (size_t)t * TPER);
    float4 v[4];
    v[0] = up[0]; v[1] = up[1]; v[2] = up[2]; v[3] = up[3];
    const float* uu = (const float*)v;

    if (FAST) {
        // ---- pure sum reduce: aggP only ----
        float p = 0.0f;
#pragma unroll
        for (int i = 0; i < TPER; ++i) p += uu[i];
#pragma unroll
        for (int off = 32; off; off >>= 1) p += __shfl_down(p, off, 64);
        if (lane == 0) LP[w] = p;
        __syncthreads();
        if (t == 0) {
            float P = 0.0f;
            for (int q = 0; q < WPB; ++q) P += LP[q];
            aggP[b] = P;
        }
    } else {
        // ---- general fallback: original verified weighted-scan aggregates ----
        float s = 0.0f, p = 0.0f;
#pragma unroll
        for (int i = 0; i < TPER; ++i) { s = fmaf(A00, s, uu[i]); p += uu[i]; }
        float fk = f16;
#pragma unroll
        for (int k = 1; k < 64; k <<= 1) {
            const float sw = __shfl_up(s, k, 64);
            const float pw = __shfl_up(p, k, 64);
            if (lane >= k) { s = fmaf(sw, fk, s); p += pw; }
            fk *= fk;
        }
        if (lane == 63) { LW[w] = s; LP[w] = p; }
        __syncthreads();
        if (t == 0) {
            float f1024 = f16;
            for (int i = 0; i < 6; ++i) f1024 *= f1024;
            float W = LW[0], P = LP[0];
            for (int q = 1; q < WPB; ++q) { W = fmaf(W, f1024, LW[q]); P += LP[q]; }
            aggW[b] = W; aggP[b] = P;
        }
    }
}

// ---------------- Kernel B: carry assemble + rescan + emit ----------------
__global__ __launch_bounds__(BLOCK, 4) void kB_emit(
    const float* __restrict__ u,
    const float* __restrict__ Rp_p, const float* __restrict__ Cp_p,
    const float* __restrict__ R0_p, const float* __restrict__ ac,
    const float* __restrict__ aggW, const float* __restrict__ aggP,
    float* __restrict__ out)
{
    __shared__ float LW[WPB], LP[WPB];
    __shared__ float sRed[WPB];
    __shared__ float sCW;

    const int b = blockIdx.x, t = threadIdx.x;
    const int lane = t & 63, w = t >> 6;

    const float Rp  = Rp_p[0];
    const float invRC = 1.0f / (Rp * Cp_p[0]);
    const float A00 = __expf(-invRC);
    const float B0  = Rp * (1.0f - A00);
    const float B1  = -1.0f / 5400.0f;                   // -eta*dt/(1.5*3600)
    const float a2 = A00 * A00, a4 = a2 * a2, a8 = a4 * a4;
    const float f16 = a8 * a8;                           // A00^16
    const float f32p = f16 * f16, f64p = f32p * f32p;    // A00^32, A00^64
    const float f128 = f64p * f64p;                      // A00^128
    const bool FAST = (f128 == 0.0f);
    float f1024 = f16;
    for (int i = 0; i < 6; ++i) f1024 *= f1024;          // A00^1024 (0.0f here)
    const float dC = (f1024 * f1024) * (f1024 * f1024);  // A00^CHUNK (0.0f here)

    // ---- own chunk loads (float4 x4 = 64 B/lane) ----
    const size_t base = (size_t)b * CHUNK + (size_t)t * TPER;
    const float4* up = (const float4*)(u + base);
    float4 v[4];
    v[0] = up[0]; v[1] = up[1]; v[2] = up[2]; v[3] = up[3];
    const float* uu = (const float*)v;

    // ---- carryP partial: block-parallel fixed-order reduce of aggP[0..b) ----
    float pc = 0.0f;
#pragma unroll
    for (int i = 0; i < APT; ++i) {
        const int j = t * APT + i;
        if (j < b) pc += aggP[j];
    }
#pragma unroll
    for (int off = 32; off; off >>= 1) pc += __shfl_down(pc, off, 64);
    if (lane == 0) sRed[w] = pc;

    // ---- carryW: halo recompute (wave 0), no aggW dependency on fast path ----
    if (FAST) {
        if (w == 0) {
            float hw = 0.0f;
            if (b > 0) {
                const float* ub = u + (size_t)b * CHUNK;
                const float a = ub[-1  - lane];          // distance d = lane+1
                const float c = ub[-65 - lane];          // distance d = lane+65
                float fl = 1.0f, bse = A00;              // A00^lane (sq-multiply)
#pragma unroll
                for (int k = 0; k < 6; ++k) { if (lane & (1 << k)) fl *= bse; bse *= bse; }
                hw = fl * fmaf(c, f64p, a);              // A00^l*u[.-1-l] + A00^(l+64)*u[.-65-l]
#pragma unroll
                for (int off = 32; off; off >>= 1) hw += __shfl_down(hw, off, 64);
            }
            if (lane == 0) sCW = hw;
        }
    } else {
        // general fallback: original aggW chain
        if (t == 0) {
            float cW = 0.0f;
            if (b > 0) {
                if (dC == 0.0f) {
                    cW = aggW[b - 1];
                } else {
                    for (int j = 0; j < b; ++j) cW = fmaf(cW, dC, aggW[j]);
                }
            }
            sCW = cW;
        }
    }

    // ---- thread aggregates + wave shuffle scan (weighted W, plain P) ----
    float s = 0.0f, p = 0.0f;
#pragma unroll
    for (int i = 0; i < TPER; ++i) { s = fmaf(A00, s, uu[i]); p += uu[i]; }
    float fk = f16;
#pragma unroll
    for (int k = 1; k < 64; k <<= 1) {
        const float sw = __shfl_up(s, k, 64);
        const float pw = __shfl_up(p, k, 64);
        if (lane >= k) { s = fmaf(sw, fk, s); p += pw; }
        fk *= fk;
    }
    if (lane == 63) { LW[w] = s; LP[w] = p; }
    __syncthreads();                                     // the ONLY barrier

    // ---- assemble per-thread exclusive prefixes ----
    float carryP_blk = 0.0f;
#pragma unroll
    for (int q = 0; q < WPB; ++q) carryP_blk += sRed[q];

    float cw = 0.0f, cp = 0.0f;                          // previous-wave carries
    for (int q = 0; q < w; ++q) { cw = fmaf(cw, f1024, LW[q]); cp += LP[q]; }

    float fw = 1.0f;                                     // f1024^w
    for (int q = 0; q < w; ++q) fw *= f1024;

    float fl = 1.0f, bse = f16;                          // f16^lane (square-multiply)
#pragma unroll
    for (int k = 0; k < 6; ++k) { if (lane & (1 << k)) fl *= bse; bse *= bse; }

    const float upW = __shfl_up(s, 1, 64);
    const float upP = __shfl_up(p, 1, 64);
    float Wcur = (lane ? upW : 0.0f) + fmaf(sCW, fw, cw) * fl;  // W at elem base
    float Pcur = (lane ? upP : 0.0f) + cp + carryP_blk;         // P at elem base

    // ---- emit 16 outputs/thread ----
    const float R0f = R0_p[0];
    float af[9];
#pragma unroll
    for (int i = 0; i < 9; ++i) af[i] = ac[i];

    float4 o[4];
    float* oy = (float*)o;
#pragma unroll
    for (int i = 0; i < TPER; ++i) {
        const float x2 = fmaf(B1, Pcur, 1.0f);           // INITIAL_X2 = 1
        float poly = af[8];
#pragma unroll
        for (int j = 7; j >= 0; --j) poly = fmaf(poly, x2, af[j]);
        oy[i] = poly - B0 * Wcur - R0f * uu[i];
        Wcur = fmaf(A00, Wcur, uu[i]);                   // emit state BEFORE update
        Pcur += uu[i];
    }
    float4* op = (float4*)(out + base);
    op[0] = o[0]; op[1] = o[1]; op[2] = o[2]; op[3] = o[3];
}

extern "C" void kernel_launch(void* const* d_in, const int* in_sizes, int n_in,
                              void* d_out, int out_size, void* d_ws, size_t ws_size,
                              hipStream_t stream) {
    const float* u    = (const float*)d_in[0];
    const float* Rp_p = (const float*)d_in[1];
    const float* Cp_p = (const float*)d_in[2];
    const float* R0_p = (const float*)d_in[3];
    const float* ac   = (const float*)d_in[4];
    float* out = (float*)d_out;

    float* wsW = (float*)d_ws;        // [NB]
    float* wsP = (float*)d_ws + NB;   // [NB]

    kA_agg <<<NB, BLOCK, 0, stream>>>(u, Rp_p, Cp_p, wsW, wsP);
    kB_emit<<<NB, BLOCK, 0, stream>>>(u, Rp_p, Cp_p, R0_p, ac, wsW, wsP, out);
}